// Round 3
// baseline (1040.506 us; speedup 1.0000x reference)
//
#include <hip/hip_runtime.h>
#include <hip/hip_bf16.h>

#define BB 8
#define NN 1024
#define FIN 256
#define FOUT 64
#define NEGV (-9000000000000000.0f)

typedef __hip_bfloat16 bf16;

__device__ __forceinline__ float b2f(bf16 v) { return __bfloat162float(v); }

__device__ __forceinline__ float waveRedSum(float v) {
  for (int d = 32; d; d >>= 1) v += __shfl_down(v, d);
  return v;
}
__device__ __forceinline__ float waveRedMax(float v) {
  for (int d = 32; d; d >>= 1) v = fmaxf(v, __shfl_down(v, d));
  return v;
}
__device__ __forceinline__ float waveRedMin(float v) {
  for (int d = 32; d; d >>= 1) v = fminf(v, __shfl_down(v, d));
  return v;
}

// block = 256 threads (4 waves), tmp = __shared__ float[4]
__device__ __forceinline__ float blockSumF(float v, float* tmp) {
  __syncthreads();
  v = waveRedSum(v);
  if ((threadIdx.x & 63) == 0) tmp[threadIdx.x >> 6] = v;
  __syncthreads();
  return tmp[0] + tmp[1] + tmp[2] + tmp[3];
}
__device__ __forceinline__ float blockMaxF(float v, float* tmp) {
  __syncthreads();
  v = waveRedMax(v);
  if ((threadIdx.x & 63) == 0) tmp[threadIdx.x >> 6] = v;
  __syncthreads();
  return fmaxf(fmaxf(tmp[0], tmp[1]), fmaxf(tmp[2], tmp[3]));
}
__device__ __forceinline__ float blockMinF(float v, float* tmp) {
  __syncthreads();
  v = waveRedMin(v);
  if ((threadIdx.x & 63) == 0) tmp[threadIdx.x >> 6] = v;
  __syncthreads();
  return fminf(fminf(tmp[0], tmp[1]), fminf(tmp[2], tmp[3]));
}

// Sentinel fill: writes `pat` to n 16-bit slots of out
__global__ void k_fill(unsigned short* o, int n, unsigned short pat) {
  int i = blockIdx.x * blockDim.x + threadIdx.x;
  int stride = gridDim.x * blockDim.x;
  for (; i < n; i += stride) o[i] = pat;
}

// Dtype probe: read x as bf16; true-bf16 data is tame, f32-underneath is not.
__global__ void k_detect(const unsigned short* xu, float* flag) {
  const int tid = threadIdx.x;
  float mx = 0.0f;
  float zc = 0.0f;
  for (int i = tid; i < 8192; i += 256) {
    unsigned short u = xu[i];
    bf16 bv = *(const bf16*)&u;
    float v = b2f(bv);
    if (u == 0 || u == 0x8000) zc += 1.0f;
    mx = fmaxf(mx, fabsf(v));
  }
  __shared__ float tmp[4];
  float gm = blockMaxF(mx, tmp);
  float gz = blockSumF(zc, tmp);
  if (tid == 0) flag[0] = (gm > 1.0e6f || gz > 2048.0f) ? 1.0f : 0.0f;
}

// K1: h = x @ W per (b,n) row; sq = |h|^2; wh1 = h.a1; wh2 = h.a2
__global__ void __launch_bounds__(64) k_h(const void* xv, const void* Wv,
                                          const void* av,
                                          const float* __restrict__ flag,
                                          float* __restrict__ h,
                                          float* __restrict__ sq,
                                          float* __restrict__ wh1,
                                          float* __restrict__ wh2) {
  const int bn = blockIdx.x;  // 0..8191
  const int o = threadIdx.x;  // 0..63
  const bool f32m = (flag[0] != 0.0f);
  __shared__ float xs[FIN];
  if (f32m) {
    const float* xr = (const float*)xv + (size_t)bn * FIN;
    for (int i = o; i < FIN; i += 64) xs[i] = xr[i];
  } else {
    const bf16* xr = (const bf16*)xv + (size_t)bn * FIN;
    for (int i = o; i < FIN; i += 64) xs[i] = b2f(xr[i]);
  }
  __syncthreads();
  float acc = 0.f;
  if (f32m) {
    const float* Wf = (const float*)Wv;
    for (int i = 0; i < FIN; ++i) acc += xs[i] * Wf[i * FOUT + o];
  } else {
    const bf16* Wb = (const bf16*)Wv;
    for (int i = 0; i < FIN; ++i) acc += xs[i] * b2f(Wb[i * FOUT + o]);
  }
  h[(size_t)bn * FOUT + o] = acc;
  float a1, a2;
  if (f32m) {
    a1 = ((const float*)av)[o];
    a2 = ((const float*)av)[FOUT + o];
  } else {
    a1 = b2f(((const bf16*)av)[o]);
    a2 = b2f(((const bf16*)av)[FOUT + o]);
  }
  float s = waveRedSum(acc * acc);
  float w1 = waveRedSum(acc * a1);
  float w2 = waveRedSum(acc * a2);
  if (o == 0) {
    sq[bn] = s;
    wh1[bn] = w1;
    wh2[bn] = w2;
  }
}

// K2 (per batch): A[n,m] = exp(-dist(n,m)); exact 1.0 on the diagonal.
__global__ void __launch_bounds__(256) k_g(const float* __restrict__ hb,
                                           const float* __restrict__ sqb,
                                           float* __restrict__ A) {
  const int tr = blockIdx.y * 64, tc = blockIdx.x * 64;
  __shared__ float Ah[64][68];
  __shared__ float Bh[64][68];
  const int tid = threadIdx.x;
  const int tx = tid & 15, ty = tid >> 4;
  for (int s = 0; s < 4; ++s) {
    int slot = tid + (s << 8);
    int r = slot >> 4;
    int c4 = (slot & 15) << 2;
    float4 va = *(const float4*)&hb[(size_t)(tr + r) * FOUT + c4];
    float4 vb = *(const float4*)&hb[(size_t)(tc + r) * FOUT + c4];
    Ah[r][c4] = va.x; Ah[r][c4 + 1] = va.y; Ah[r][c4 + 2] = va.z; Ah[r][c4 + 3] = va.w;
    Bh[r][c4] = vb.x; Bh[r][c4 + 1] = vb.y; Bh[r][c4 + 2] = vb.z; Bh[r][c4 + 3] = vb.w;
  }
  __syncthreads();
  float acc[4][4] = {};
  for (int k = 0; k < 64; ++k) {
    float ra[4], rb[4];
    for (int i = 0; i < 4; ++i) ra[i] = Ah[ty * 4 + i][k];
    for (int j = 0; j < 4; ++j) rb[j] = Bh[tx * 4 + j][k];
    for (int i = 0; i < 4; ++i)
      for (int j = 0; j < 4; ++j) acc[i][j] += ra[i] * rb[j];
  }
  for (int i = 0; i < 4; ++i) {
    int n = tr + ty * 4 + i;
    float sn = sqb[n];
    for (int j = 0; j < 4; ++j) {
      int m = tc + tx * 4 + j;
      float d2 = sn + sqb[m] - 2.0f * acc[i][j];
      float val = (n == m) ? 1.0f : ((d2 > 0.0f) ? expf(-sqrtf(d2)) : 1.0f);
      A[(size_t)n * NN + m] = val;
    }
  }
}

// K3 (per batch): row normalize in place
__global__ void __launch_bounds__(256) k_rownorm(float* __restrict__ A) {
  const int n = blockIdx.x;
  float* row = A + (size_t)n * NN;
  __shared__ float tmp[4];
  const int tid = threadIdx.x;
  float v[4];
  float s = 0.f;
  for (int w = 0; w < 4; ++w) {
    v[w] = row[tid + (w << 8)];
    s += v[w];
  }
  s = blockSumF(s, tmp);
  float denom = fmaxf(s, 1e-12f);
  for (int w = 0; w < 4; ++w) row[tid + (w << 8)] = v[w] / denom;
}

// K4 (per batch): C = A @ B, 1024x1024 f32. 64x64 tile, 256 thr, 4x4 micro.
__global__ void __launch_bounds__(256) k_gemm64(const float* __restrict__ A,
                                                const float* __restrict__ B,
                                                float* __restrict__ C) {
  const int tr = blockIdx.y * 64, tc = blockIdx.x * 64;
  __shared__ float As[32][68];  // [k][r]
  __shared__ float Bs[32][68];  // [k][c]
  float acc[4][4] = {};
  const int tid = threadIdx.x;
  const int tx = tid & 15, ty = tid >> 4;
  for (int kc = 0; kc < NN; kc += 32) {
    if (kc) __syncthreads();
    for (int s = 0; s < 2; ++s) {
      int slot = tid + (s << 8);  // 0..511
      int r = slot >> 3;          // 0..63
      int kq = (slot & 7) << 2;   // 0..28
      float4 va = *(const float4*)&A[(size_t)(tr + r) * NN + kc + kq];
      As[kq + 0][r] = va.x;
      As[kq + 1][r] = va.y;
      As[kq + 2][r] = va.z;
      As[kq + 3][r] = va.w;
      int k = slot >> 4;          // 0..31
      int c4 = (slot & 15) << 2;  // 0..60
      float4 vb = *(const float4*)&B[(size_t)(kc + k) * NN + tc + c4];
      Bs[k][c4] = vb.x; Bs[k][c4 + 1] = vb.y; Bs[k][c4 + 2] = vb.z; Bs[k][c4 + 3] = vb.w;
    }
    __syncthreads();
    for (int k = 0; k < 32; ++k) {
      float ra[4], rb[4];
      for (int i = 0; i < 4; ++i) ra[i] = As[k][ty * 4 + i];
      for (int j = 0; j < 4; ++j) rb[j] = Bs[k][tx * 4 + j];
      for (int i = 0; i < 4; ++i)
        for (int j = 0; j < 4; ++j) acc[i][j] += ra[i] * rb[j];
    }
  }
  for (int i = 0; i < 4; ++i)
    for (int j = 0; j < 4; ++j)
      C[(size_t)(tr + ty * 4 + i) * NN + tc + tx * 4 + j] = acc[i][j];
}

// K5 (per batch): S = 0.5*(T + T^T), T = P1 + 0.8*P2 + 0.64*P3; S aliases P3.
__global__ void __launch_bounds__(256) k_sym(const float* __restrict__ P1,
                                             const float* __restrict__ P2,
                                             const float* P3, float* S) {
  int p = blockIdx.x;  // 0..527 -> (ti<=tj) pair
  int ti = 0, rem = p;
  while (rem >= 32 - ti) {
    rem -= 32 - ti;
    ++ti;
  }
  const int tj = ti + rem;
  const float c2 = 0.8f, c3 = 0.64f;
  __shared__ float D1[32][33], D2[32][33];
  const int tid = threadIdx.x;
  for (int s = 0; s < 4; ++s) {
    int slot = tid + (s << 8);
    int r = slot >> 5, c = slot & 31;
    size_t i1 = (size_t)(ti * 32 + r) * NN + tj * 32 + c;
    size_t i2 = (size_t)(tj * 32 + r) * NN + ti * 32 + c;
    D1[r][c] = P1[i1] + c2 * P2[i1] + c3 * P3[i1];
    D2[r][c] = P1[i2] + c2 * P2[i2] + c3 * P3[i2];
  }
  __syncthreads();
  for (int s = 0; s < 4; ++s) {
    int slot = tid + (s << 8);
    int r = slot >> 5, c = slot & 31;
    size_t i1 = (size_t)(ti * 32 + r) * NN + tj * 32 + c;
    size_t i2 = (size_t)(tj * 32 + r) * NN + ti * 32 + c;
    S[i1] = 0.5f * (D1[r][c] + D2[c][r]);
    S[i2] = 0.5f * (D2[r][c] + D1[c][r]);
  }
}

// K6: thr[b] = min(diag) - mean(diag[:-1] - offdiag)
__global__ void __launch_bounds__(256) k_thr(const float* __restrict__ S,
                                             float* __restrict__ thr) {
  const int b = blockIdx.x;
  const float* Sb = S + (size_t)b * NN * NN;
  const int tid = threadIdx.x;
  float mn = 3.0e38f;
  float rsum = 0.f;
  for (int n = tid; n < NN; n += 256) {
    float d = Sb[(size_t)n * NN + n];
    mn = fminf(mn, d);
    if (n < NN - 1) rsum += d - Sb[(size_t)n * NN + n + 1];
  }
  __shared__ float tmp[4];
  float mtot = blockMinF(mn, tmp);
  float stot = blockSumF(rsum, tmp);
  if (tid == 0) thr[b] = mtot - stot / 1023.0f;
}

// K7: per-n BN stats over (b,m); double accum via LDS tree (no double shfl)
__global__ void __launch_bounds__(256) k_stats(const float* __restrict__ S,
                                               const float* __restrict__ thr,
                                               const float* __restrict__ wh1,
                                               const float* __restrict__ wh2,
                                               float* __restrict__ meanv,
                                               float* __restrict__ rstdv) {
  const int n = blockIdx.x;
  const int tid = threadIdx.x;
  double s1 = 0.0, s2 = 0.0;
  for (int b = 0; b < BB; ++b) {
    float t = thr[b];
    float w1 = wh1[b * NN + n];
    const float* Srow = S + ((size_t)b * NN + n) * NN;
    const float* w2p = wh2 + b * NN;
    for (int m = tid; m < NN; m += 256) {
      float e = w1 + w2p[m];
      e = (e > 0.f) ? e : 0.01f * e;
      float att = (Srow[m] > t) ? e : NEGV;
      s1 += (double)att;
      s2 += (double)att * (double)att;
    }
  }
  __shared__ double red[256];
  red[tid] = s1;
  __syncthreads();
  for (int s = 128; s > 0; s >>= 1) {
    if (tid < s) red[tid] += red[tid + s];
    __syncthreads();
  }
  double t1 = red[0];
  __syncthreads();
  red[tid] = s2;
  __syncthreads();
  for (int s = 128; s > 0; s >>= 1) {
    if (tid < s) red[tid] += red[tid + s];
    __syncthreads();
  }
  double t2 = red[0];
  if (tid == 0) {
    double mean = t1 / 8192.0;
    double var = t2 / 8192.0 - mean * mean;
    if (var < 0.0) var = 0.0;
    meanv[n] = (float)mean;
    rstdv[n] = (float)(1.0 / sqrt(var + 1e-5));
  }
}

// K8: out[b,n,:] = softmax((att - mean[n]) * rstd[n]) over m
__global__ void __launch_bounds__(256) k_out(const float* __restrict__ S,
                                             const float* __restrict__ thr,
                                             const float* __restrict__ wh1,
                                             const float* __restrict__ wh2,
                                             const float* __restrict__ meanv,
                                             const float* __restrict__ rstdv,
                                             const float* __restrict__ flag,
                                             void* outv) {
  const int bn = blockIdx.x;
  const int b = bn >> 10;
  const int n = bn & 1023;
  const int tid = threadIdx.x;
  const bool f32m = (flag[0] != 0.0f);
  const float t = thr[b];
  const float w1 = wh1[bn];
  const float* Srow = S + (size_t)bn * NN;
  const float* w2p = wh2 + b * NN;
  float v[4];
  float mx = -3.0e38f;
  for (int w = 0; w < 4; ++w) {
    int m = tid + (w << 8);
    float e = w1 + w2p[m];
    e = (e > 0.f) ? e : 0.01f * e;
    float att = (Srow[m] > t) ? e : NEGV;
    float vv = (att - meanv[n]) * rstdv[n];
    v[w] = vv;
    mx = fmaxf(mx, vv);
  }
  __shared__ float tmp[4];
  float gmx = blockMaxF(mx, tmp);
  float sum = 0.f;
  for (int w = 0; w < 4; ++w) {
    v[w] = __expf(v[w] - gmx);
    sum += v[w];
  }
  float gsum = blockSumF(sum, tmp);
  for (int w = 0; w < 4; ++w) {
    int m = tid + (w << 8);
    float val = v[w] / gsum;
    if (f32m) {
      ((float*)outv)[(size_t)bn * NN + m] = val;
    } else {
      ((bf16*)outv)[(size_t)bn * NN + m] = __float2bfloat16(val);
    }
  }
}

extern "C" void kernel_launch(void* const* d_in, const int* in_sizes, int n_in,
                              void* d_out, int out_size, void* d_ws,
                              size_t ws_size, hipStream_t stream) {
  float* ws = (float*)d_ws;

  // float-offset layout (~42.2 MB total)
  float* sq = ws;              // 8192
  float* wh1 = ws + 8192;      // 8192
  float* wh2 = ws + 16384;     // 8192
  float* thr = ws + 24576;     // 8
  float* meanv = ws + 24584;   // 1024
  float* rstdv = ws + 25608;   // 1024
  float* flag = ws + 26632;    // 8
  float* h = ws + 32768;       // 524288
  float* A_tmp = ws + 557056;  // 1048576 (4 MB)
  float* B_tmp = ws + 1605632; // 1048576 (4 MB)
  float* S = ws + 2654208;     // 8388608 (32 MB)
  const size_t needed = (2654208ull + 8388608ull) * 4ull;  // 44,171,264 B

  // Sentinel A: bf16 0.5 everywhere. Overwritten by k_out on success.
  k_fill<<<dim3(2048), 256, 0, stream>>>((unsigned short*)d_out, out_size,
                                         (unsigned short)0x3F00);

  if (ws_size < needed) {
    // Sentinel B: bf16 -1.0 -> absmax ~1.28 signals "workspace too small"
    k_fill<<<dim3(2048), 256, 0, stream>>>((unsigned short*)d_out, out_size,
                                           (unsigned short)0xBF80);
    return;
  }

  k_detect<<<dim3(1), 256, 0, stream>>>((const unsigned short*)d_in[0], flag);
  k_h<<<dim3(BB * NN), 64, 0, stream>>>(d_in[0], d_in[1], d_in[2], flag, h, sq,
                                        wh1, wh2);
  for (int b = 0; b < BB; ++b) {
    const float* hb = h + (size_t)b * NN * FOUT;
    const float* sqb = sq + (size_t)b * NN;
    float* Sb = S + (size_t)b * NN * NN;
    k_g<<<dim3(16, 16), 256, 0, stream>>>(hb, sqb, A_tmp);
    k_rownorm<<<dim3(NN), 256, 0, stream>>>(A_tmp);
    k_gemm64<<<dim3(16, 16), 256, 0, stream>>>(A_tmp, A_tmp, B_tmp);
    k_gemm64<<<dim3(16, 16), 256, 0, stream>>>(A_tmp, B_tmp, Sb);
    k_sym<<<dim3(528), 256, 0, stream>>>(A_tmp, B_tmp, Sb, Sb);
  }
  k_thr<<<dim3(BB), 256, 0, stream>>>(S, thr);
  k_stats<<<dim3(NN), 256, 0, stream>>>(S, thr, wh1, wh2, meanv, rstdv);
  k_out<<<dim3(BB * NN), 256, 0, stream>>>(S, thr, wh1, wh2, meanv, rstdv, flag,
                                           d_out);
}

// Round 4
// 364.000 us; speedup vs baseline: 2.8585x; 2.8585x over previous
//
#include <hip/hip_runtime.h>
#include <hip/hip_bf16.h>

#define BB 8
#define NN 1024
#define FIN 256
#define FOUT 64
#define NEGV (-9000000000000000.0f)

typedef __hip_bfloat16 bf16;
typedef short bf16x8 __attribute__((ext_vector_type(8)));
typedef float f32x4 __attribute__((ext_vector_type(4)));

__device__ __forceinline__ float b2f(bf16 v) { return __bfloat162float(v); }
__device__ __forceinline__ float bu2f(unsigned short u) {
  union { unsigned int i; float f; } c;
  c.i = ((unsigned int)u) << 16;
  return c.f;
}
__device__ __forceinline__ unsigned short f2bu(float v) {
  bf16 t = __float2bfloat16(v);
  return *(unsigned short*)&t;
}

__device__ __forceinline__ float waveRedSum(float v) {
  for (int d = 32; d; d >>= 1) v += __shfl_down(v, d);
  return v;
}
__device__ __forceinline__ float waveRedMax(float v) {
  for (int d = 32; d; d >>= 1) v = fmaxf(v, __shfl_down(v, d));
  return v;
}
__device__ __forceinline__ float waveRedMin(float v) {
  for (int d = 32; d; d >>= 1) v = fminf(v, __shfl_down(v, d));
  return v;
}

__device__ __forceinline__ float blockSumF(float v, float* tmp) {
  __syncthreads();
  v = waveRedSum(v);
  if ((threadIdx.x & 63) == 0) tmp[threadIdx.x >> 6] = v;
  __syncthreads();
  return tmp[0] + tmp[1] + tmp[2] + tmp[3];
}
__device__ __forceinline__ float blockMaxF(float v, float* tmp) {
  __syncthreads();
  v = waveRedMax(v);
  if ((threadIdx.x & 63) == 0) tmp[threadIdx.x >> 6] = v;
  __syncthreads();
  return fmaxf(fmaxf(tmp[0], tmp[1]), fmaxf(tmp[2], tmp[3]));
}
__device__ __forceinline__ float blockMinF(float v, float* tmp) {
  __syncthreads();
  v = waveRedMin(v);
  if ((threadIdx.x & 63) == 0) tmp[threadIdx.x >> 6] = v;
  __syncthreads();
  return fminf(fminf(tmp[0], tmp[1]), fminf(tmp[2], tmp[3]));
}

__global__ void k_fill(unsigned short* o, int n, unsigned short pat) {
  int i = blockIdx.x * blockDim.x + threadIdx.x;
  int stride = gridDim.x * blockDim.x;
  for (; i < n; i += stride) o[i] = pat;
}

__global__ void k_detect(const unsigned short* xu, float* flag) {
  const int tid = threadIdx.x;
  float mx = 0.0f, zc = 0.0f;
  for (int i = tid; i < 8192; i += 256) {
    unsigned short u = xu[i];
    float v = bu2f(u);
    if (u == 0 || u == 0x8000) zc += 1.0f;
    mx = fmaxf(mx, fabsf(v));
  }
  __shared__ float tmp[4];
  float gm = blockMaxF(mx, tmp);
  float gz = blockSumF(zc, tmp);
  if (tid == 0) flag[0] = (gm > 1.0e6f || gz > 2048.0f) ? 1.0f : 0.0f;
}

// h = x @ W per (b,n) row; sq = |h|^2; wh1 = h.a1; wh2 = h.a2
__global__ void __launch_bounds__(64) k_h(const void* xv, const void* Wv,
                                          const void* av,
                                          const float* __restrict__ flag,
                                          float* __restrict__ h,
                                          float* __restrict__ sq,
                                          float* __restrict__ wh1,
                                          float* __restrict__ wh2) {
  const int bn = blockIdx.x;
  const int o = threadIdx.x;
  const bool f32m = (flag[0] != 0.0f);
  __shared__ float xs[FIN];
  if (f32m) {
    const float* xr = (const float*)xv + (size_t)bn * FIN;
    for (int i = o; i < FIN; i += 64) xs[i] = xr[i];
  } else {
    const bf16* xr = (const bf16*)xv + (size_t)bn * FIN;
    for (int i = o; i < FIN; i += 64) xs[i] = b2f(xr[i]);
  }
  __syncthreads();
  float acc = 0.f;
  if (f32m) {
    const float* Wf = (const float*)Wv;
    for (int i = 0; i < FIN; ++i) acc += xs[i] * Wf[i * FOUT + o];
  } else {
    const bf16* Wb = (const bf16*)Wv;
    for (int i = 0; i < FIN; ++i) acc += xs[i] * b2f(Wb[i * FOUT + o]);
  }
  h[(size_t)bn * FOUT + o] = acc;
  float a1, a2;
  if (f32m) {
    a1 = ((const float*)av)[o];
    a2 = ((const float*)av)[FOUT + o];
  } else {
    a1 = b2f(((const bf16*)av)[o]);
    a2 = b2f(((const bf16*)av)[FOUT + o]);
  }
  float s = waveRedSum(acc * acc);
  float w1 = waveRedSum(acc * a1);
  float w2 = waveRedSum(acc * a2);
  if (o == 0) {
    sq[bn] = s;
    wh1[bn] = w1;
    wh2[bn] = w2;
  }
}

// batched: A_un[z][n][m] = exp(-dist); exact 1.0 on diagonal
__global__ void __launch_bounds__(256) k_g(const float* __restrict__ h,
                                           const float* __restrict__ sq,
                                           float* __restrict__ A) {
  const int z = blockIdx.z;
  const float* hb = h + (size_t)z * NN * FOUT;
  const float* sqb = sq + (size_t)z * NN;
  float* Ab = A + (size_t)z * NN * NN;
  const int tr = blockIdx.y * 64, tc = blockIdx.x * 64;
  __shared__ float Ah[64][68];
  __shared__ float Bh[64][68];
  const int tid = threadIdx.x;
  const int tx = tid & 15, ty = tid >> 4;
  for (int s = 0; s < 4; ++s) {
    int slot = tid + (s << 8);
    int r = slot >> 4;
    int c4 = (slot & 15) << 2;
    float4 va = *(const float4*)&hb[(size_t)(tr + r) * FOUT + c4];
    float4 vb = *(const float4*)&hb[(size_t)(tc + r) * FOUT + c4];
    Ah[r][c4] = va.x; Ah[r][c4 + 1] = va.y; Ah[r][c4 + 2] = va.z; Ah[r][c4 + 3] = va.w;
    Bh[r][c4] = vb.x; Bh[r][c4 + 1] = vb.y; Bh[r][c4 + 2] = vb.z; Bh[r][c4 + 3] = vb.w;
  }
  __syncthreads();
  float acc[4][4] = {};
  for (int k = 0; k < 64; ++k) {
    float ra[4], rb[4];
    for (int i = 0; i < 4; ++i) ra[i] = Ah[ty * 4 + i][k];
    for (int j = 0; j < 4; ++j) rb[j] = Bh[tx * 4 + j][k];
    for (int i = 0; i < 4; ++i)
      for (int j = 0; j < 4; ++j) acc[i][j] += ra[i] * rb[j];
  }
  for (int i = 0; i < 4; ++i) {
    int n = tr + ty * 4 + i;
    float sn = sqb[n];
    for (int j = 0; j < 4; ++j) {
      int m = tc + tx * 4 + j;
      float d2 = sn + sqb[m] - 2.0f * acc[i][j];
      float val = (n == m) ? 1.0f : ((d2 > 0.0f) ? expf(-sqrtf(d2)) : 1.0f);
      Ab[(size_t)n * NN + m] = val;
    }
  }
}

// slow path: normalize src row -> dst
__global__ void __launch_bounds__(256) k_rownorm2(const float* __restrict__ src,
                                                  float* __restrict__ dst) {
  const int n = blockIdx.x;
  const float* row = src + (size_t)n * NN;
  float* drow = dst + (size_t)n * NN;
  __shared__ float tmp[4];
  const int tid = threadIdx.x;
  float v[4];
  float s = 0.f;
  for (int w = 0; w < 4; ++w) {
    v[w] = row[tid + (w << 8)];
    s += v[w];
  }
  s = blockSumF(s, tmp);
  float denom = fmaxf(s, 1e-12f);
  for (int w = 0; w < 4; ++w) drow[tid + (w << 8)] = v[w] / denom;
}

// fast path: row sums of unnormalized A (all batches)
__global__ void __launch_bounds__(256) k_rowsum(const float* __restrict__ A,
                                                float* __restrict__ rsum) {
  const int bn = blockIdx.x;  // 0..8191
  const float* row = A + (size_t)bn * NN;
  __shared__ float tmp[4];
  const int tid = threadIdx.x;
  float s = 0.f;
  for (int w = 0; w < 4; ++w) s += row[tid + (w << 8)];
  s = blockSumF(s, tmp);
  if (tid == 0) rsum[bn] = fmaxf(s, 1e-12f);
}

// fast path: normalize + split hi/lo bf16, normal and transposed layouts
__global__ void __launch_bounds__(256) k_split(const float* __restrict__ A,
                                               const float* __restrict__ rsum,
                                               unsigned short* __restrict__ Ah,
                                               unsigned short* __restrict__ Al,
                                               unsigned short* __restrict__ ATh,
                                               unsigned short* __restrict__ ATl) {
  const int z = blockIdx.z;
  const size_t MAT = (size_t)NN * NN;
  const float* Ab = A + z * MAT;
  const float* rs = rsum + (size_t)z * NN;
  unsigned short* ah = Ah + z * MAT;
  unsigned short* al = Al + z * MAT;
  unsigned short* ath = ATh + z * MAT;
  unsigned short* atl = ATl + z * MAT;
  const int rt = blockIdx.y * 32, ct = blockIdx.x * 32;
  __shared__ unsigned short th[32][33], tl[32][33];
  const int tid = threadIdx.x;
  {
    int r = tid >> 3;            // 0..31
    int c0 = (tid & 7) << 2;     // 0..28
    float4 v = *(const float4*)&Ab[(size_t)(rt + r) * NN + ct + c0];
    float inv = 1.0f / rs[rt + r];
    float vv[4] = {v.x * inv, v.y * inv, v.z * inv, v.w * inv};
    ushort4 h4, l4;
    unsigned short hs[4], ls[4];
    for (int k = 0; k < 4; ++k) {
      hs[k] = f2bu(vv[k]);
      ls[k] = f2bu(vv[k] - bu2f(hs[k]));
      th[r][c0 + k] = hs[k];
      tl[r][c0 + k] = ls[k];
    }
    h4.x = hs[0]; h4.y = hs[1]; h4.z = hs[2]; h4.w = hs[3];
    l4.x = ls[0]; l4.y = ls[1]; l4.z = ls[2]; l4.w = ls[3];
    *(ushort4*)&ah[(size_t)(rt + r) * NN + ct + c0] = h4;
    *(ushort4*)&al[(size_t)(rt + r) * NN + ct + c0] = l4;
  }
  __syncthreads();
  {
    int c = tid >> 3;            // 0..31
    int r0 = (tid & 7) << 2;     // 0..28
    ushort4 h4, l4;
    h4.x = th[r0][c]; h4.y = th[r0 + 1][c]; h4.z = th[r0 + 2][c]; h4.w = th[r0 + 3][c];
    l4.x = tl[r0][c]; l4.y = tl[r0 + 1][c]; l4.z = tl[r0 + 2][c]; l4.w = tl[r0 + 3][c];
    *(ushort4*)&ath[(size_t)(ct + c) * NN + rt + r0] = h4;
    *(ushort4*)&atl[(size_t)(ct + c) * NN + rt + r0] = l4;
  }
}

// MFMA GEMM1: C = A*A (split bf16); writes C transposed (hi/lo bf16)
__global__ void __launch_bounds__(256) k_mm1(
    const unsigned short* __restrict__ Ah, const unsigned short* __restrict__ Al,
    const unsigned short* __restrict__ ATh, const unsigned short* __restrict__ ATl,
    unsigned short* __restrict__ CTh, unsigned short* __restrict__ CTl) {
  const int z = blockIdx.z;
  const size_t MAT = (size_t)NN * NN;
  const unsigned short* ah = Ah + z * MAT;
  const unsigned short* al = Al + z * MAT;
  const unsigned short* bh = ATh + z * MAT;
  const unsigned short* bl = ATl + z * MAT;
  unsigned short* cth = CTh + z * MAT;
  unsigned short* ctl = CTl + z * MAT;
  const int tr = blockIdx.y * 128, tc = blockIdx.x * 128;
  __shared__ unsigned short sAh[128 * 40], sAl[128 * 40];
  __shared__ unsigned short sBh[128 * 40], sBl[128 * 40];
  f32x4 acc[4][4];
  for (int i = 0; i < 4; ++i)
    for (int j = 0; j < 4; ++j) acc[i][j] = (f32x4){0.f, 0.f, 0.f, 0.f};
  const int tid = threadIdx.x;
  const int wave = tid >> 6, lane = tid & 63;
  const int wm = (wave >> 1) * 64, wn = (wave & 1) * 64;
  const int q = lane >> 4, ln = lane & 15;
  const int r0 = tid >> 2;
  const int k8 = (tid & 3) << 3;
  for (int kc = 0; kc < NN; kc += 32) {
    __syncthreads();
    for (int p = 0; p < 2; ++p) {
      int r = r0 + p * 64;
      *(bf16x8*)&sAh[r * 40 + k8] = *(const bf16x8*)&ah[(size_t)(tr + r) * NN + kc + k8];
      *(bf16x8*)&sAl[r * 40 + k8] = *(const bf16x8*)&al[(size_t)(tr + r) * NN + kc + k8];
      *(bf16x8*)&sBh[r * 40 + k8] = *(const bf16x8*)&bh[(size_t)(tc + r) * NN + kc + k8];
      *(bf16x8*)&sBl[r * 40 + k8] = *(const bf16x8*)&bl[(size_t)(tc + r) * NN + kc + k8];
    }
    __syncthreads();
    bf16x8 fah[4], fal[4], fbh[4], fbl[4];
    for (int i = 0; i < 4; ++i) {
      fah[i] = *(const bf16x8*)&sAh[(wm + i * 16 + ln) * 40 + q * 8];
      fal[i] = *(const bf16x8*)&sAl[(wm + i * 16 + ln) * 40 + q * 8];
    }
    for (int j = 0; j < 4; ++j) {
      fbh[j] = *(const bf16x8*)&sBh[(wn + j * 16 + ln) * 40 + q * 8];
      fbl[j] = *(const bf16x8*)&sBl[(wn + j * 16 + ln) * 40 + q * 8];
    }
    for (int i = 0; i < 4; ++i)
      for (int j = 0; j < 4; ++j) {
        acc[i][j] = __builtin_amdgcn_mfma_f32_16x16x32_bf16(fah[i], fbh[j], acc[i][j], 0, 0, 0);
        acc[i][j] = __builtin_amdgcn_mfma_f32_16x16x32_bf16(fah[i], fbl[j], acc[i][j], 0, 0, 0);
        acc[i][j] = __builtin_amdgcn_mfma_f32_16x16x32_bf16(fal[i], fbh[j], acc[i][j], 0, 0, 0);
      }
  }
  for (int i = 0; i < 4; ++i) {
    int m0 = tr + wm + i * 16 + q * 4;
    for (int j = 0; j < 4; ++j) {
      int n = tc + wn + j * 16 + ln;
      ushort4 h4, l4;
      unsigned short hs[4], ls[4];
      for (int reg = 0; reg < 4; ++reg) {
        float v = acc[i][j][reg];
        hs[reg] = f2bu(v);
        ls[reg] = f2bu(v - bu2f(hs[reg]));
      }
      h4.x = hs[0]; h4.y = hs[1]; h4.z = hs[2]; h4.w = hs[3];
      l4.x = ls[0]; l4.y = ls[1]; l4.z = ls[2]; l4.w = ls[3];
      *(ushort4*)&cth[(size_t)n * NN + m0] = h4;
      *(ushort4*)&ctl[(size_t)n * NN + m0] = l4;
    }
  }
}

// MFMA GEMM2: T = A + 0.8*C + 0.64*(A*C) -> S (f32)
__global__ void __launch_bounds__(256) k_mm2(
    const unsigned short* __restrict__ Ah, const unsigned short* __restrict__ Al,
    const unsigned short* __restrict__ ATh, const unsigned short* __restrict__ ATl,
    const unsigned short* __restrict__ CTh, const unsigned short* __restrict__ CTl,
    float* __restrict__ S) {
  const int z = blockIdx.z;
  const size_t MAT = (size_t)NN * NN;
  const unsigned short* ah = Ah + z * MAT;
  const unsigned short* al = Al + z * MAT;
  const unsigned short* ath = ATh + z * MAT;
  const unsigned short* atl = ATl + z * MAT;
  const unsigned short* bh = CTh + z * MAT;
  const unsigned short* bl = CTl + z * MAT;
  float* Sb = S + z * MAT;
  const int tr = blockIdx.y * 128, tc = blockIdx.x * 128;
  __shared__ unsigned short sAh[128 * 40], sAl[128 * 40];
  __shared__ unsigned short sBh[128 * 40], sBl[128 * 40];
  f32x4 acc[4][4];
  for (int i = 0; i < 4; ++i)
    for (int j = 0; j < 4; ++j) acc[i][j] = (f32x4){0.f, 0.f, 0.f, 0.f};
  const int tid = threadIdx.x;
  const int wave = tid >> 6, lane = tid & 63;
  const int wm = (wave >> 1) * 64, wn = (wave & 1) * 64;
  const int q = lane >> 4, ln = lane & 15;
  const int r0 = tid >> 2;
  const int k8 = (tid & 3) << 3;
  for (int kc = 0; kc < NN; kc += 32) {
    __syncthreads();
    for (int p = 0; p < 2; ++p) {
      int r = r0 + p * 64;
      *(bf16x8*)&sAh[r * 40 + k8] = *(const bf16x8*)&ah[(size_t)(tr + r) * NN + kc + k8];
      *(bf16x8*)&sAl[r * 40 + k8] = *(const bf16x8*)&al[(size_t)(tr + r) * NN + kc + k8];
      *(bf16x8*)&sBh[r * 40 + k8] = *(const bf16x8*)&bh[(size_t)(tc + r) * NN + kc + k8];
      *(bf16x8*)&sBl[r * 40 + k8] = *(const bf16x8*)&bl[(size_t)(tc + r) * NN + kc + k8];
    }
    __syncthreads();
    bf16x8 fah[4], fal[4], fbh[4], fbl[4];
    for (int i = 0; i < 4; ++i) {
      fah[i] = *(const bf16x8*)&sAh[(wm + i * 16 + ln) * 40 + q * 8];
      fal[i] = *(const bf16x8*)&sAl[(wm + i * 16 + ln) * 40 + q * 8];
    }
    for (int j = 0; j < 4; ++j) {
      fbh[j] = *(const bf16x8*)&sBh[(wn + j * 16 + ln) * 40 + q * 8];
      fbl[j] = *(const bf16x8*)&sBl[(wn + j * 16 + ln) * 40 + q * 8];
    }
    for (int i = 0; i < 4; ++i)
      for (int j = 0; j < 4; ++j) {
        acc[i][j] = __builtin_amdgcn_mfma_f32_16x16x32_bf16(fah[i], fbh[j], acc[i][j], 0, 0, 0);
        acc[i][j] = __builtin_amdgcn_mfma_f32_16x16x32_bf16(fah[i], fbl[j], acc[i][j], 0, 0, 0);
        acc[i][j] = __builtin_amdgcn_mfma_f32_16x16x32_bf16(fal[i], fbh[j], acc[i][j], 0, 0, 0);
      }
  }
  for (int i = 0; i < 4; ++i) {
    int m0 = tr + wm + i * 16 + q * 4;
    for (int j = 0; j < 4; ++j) {
      int n = tc + wn + j * 16 + ln;
      ushort4 a_h = *(const ushort4*)&ath[(size_t)n * NN + m0];
      ushort4 a_l = *(const ushort4*)&atl[(size_t)n * NN + m0];
      ushort4 c_h = *(const ushort4*)&bh[(size_t)n * NN + m0];
      ushort4 c_l = *(const ushort4*)&bl[(size_t)n * NN + m0];
      unsigned short ahv[4] = {a_h.x, a_h.y, a_h.z, a_h.w};
      unsigned short alv[4] = {a_l.x, a_l.y, a_l.z, a_l.w};
      unsigned short chv[4] = {c_h.x, c_h.y, c_h.z, c_h.w};
      unsigned short clv[4] = {c_l.x, c_l.y, c_l.z, c_l.w};
      for (int reg = 0; reg < 4; ++reg) {
        float av = bu2f(ahv[reg]) + bu2f(alv[reg]);
        float cv = bu2f(chv[reg]) + bu2f(clv[reg]);
        float t = av + 0.8f * cv + 0.64f * acc[i][j][reg];
        Sb[(size_t)(m0 + reg) * NN + n] = t;
      }
    }
  }
}

// fast path: in-place symmetrize S = 0.5*(S + S^T), pair tiles
__global__ void __launch_bounds__(256) k_sym_ip(float* __restrict__ S) {
  const int z = blockIdx.y;
  float* Sb = S + (size_t)z * NN * NN;
  int p = blockIdx.x;
  int ti = 0, rem = p;
  while (rem >= 32 - ti) {
    rem -= 32 - ti;
    ++ti;
  }
  const int tj = ti + rem;
  __shared__ float D1[32][33], D2[32][33];
  const int tid = threadIdx.x;
  for (int s = 0; s < 4; ++s) {
    int slot = tid + (s << 8);
    int r = slot >> 5, c = slot & 31;
    D1[r][c] = Sb[(size_t)(ti * 32 + r) * NN + tj * 32 + c];
    D2[r][c] = Sb[(size_t)(tj * 32 + r) * NN + ti * 32 + c];
  }
  __syncthreads();
  for (int s = 0; s < 4; ++s) {
    int slot = tid + (s << 8);
    int r = slot >> 5, c = slot & 31;
    Sb[(size_t)(ti * 32 + r) * NN + tj * 32 + c] = 0.5f * (D1[r][c] + D2[c][r]);
    Sb[(size_t)(tj * 32 + r) * NN + ti * 32 + c] = 0.5f * (D2[r][c] + D1[c][r]);
  }
}

// slow path f32 GEMM (proven)
__global__ void __launch_bounds__(256) k_gemm64(const float* __restrict__ A,
                                                const float* __restrict__ B,
                                                float* __restrict__ C) {
  const int tr = blockIdx.y * 64, tc = blockIdx.x * 64;
  __shared__ float As[32][68];
  __shared__ float Bs[32][68];
  float acc[4][4] = {};
  const int tid = threadIdx.x;
  const int tx = tid & 15, ty = tid >> 4;
  for (int kc = 0; kc < NN; kc += 32) {
    if (kc) __syncthreads();
    for (int s = 0; s < 2; ++s) {
      int slot = tid + (s << 8);
      int r = slot >> 3;
      int kq = (slot & 7) << 2;
      float4 va = *(const float4*)&A[(size_t)(tr + r) * NN + kc + kq];
      As[kq + 0][r] = va.x;
      As[kq + 1][r] = va.y;
      As[kq + 2][r] = va.z;
      As[kq + 3][r] = va.w;
      int k = slot >> 4;
      int c4 = (slot & 15) << 2;
      float4 vb = *(const float4*)&B[(size_t)(kc + k) * NN + tc + c4];
      Bs[k][c4] = vb.x; Bs[k][c4 + 1] = vb.y; Bs[k][c4 + 2] = vb.z; Bs[k][c4 + 3] = vb.w;
    }
    __syncthreads();
    for (int k = 0; k < 32; ++k) {
      float ra[4], rb[4];
      for (int i = 0; i < 4; ++i) ra[i] = As[k][ty * 4 + i];
      for (int j = 0; j < 4; ++j) rb[j] = Bs[k][tx * 4 + j];
      for (int i = 0; i < 4; ++i)
        for (int j = 0; j < 4; ++j) acc[i][j] += ra[i] * rb[j];
    }
  }
  for (int i = 0; i < 4; ++i)
    for (int j = 0; j < 4; ++j)
      C[(size_t)(tr + ty * 4 + i) * NN + tc + tx * 4 + j] = acc[i][j];
}

// slow path combine+symmetrize
__global__ void __launch_bounds__(256) k_sym(const float* __restrict__ P1,
                                             const float* __restrict__ P2,
                                             const float* P3, float* S) {
  int p = blockIdx.x;
  int ti = 0, rem = p;
  while (rem >= 32 - ti) {
    rem -= 32 - ti;
    ++ti;
  }
  const int tj = ti + rem;
  const float c2 = 0.8f, c3 = 0.64f;
  __shared__ float D1[32][33], D2[32][33];
  const int tid = threadIdx.x;
  for (int s = 0; s < 4; ++s) {
    int slot = tid + (s << 8);
    int r = slot >> 5, c = slot & 31;
    size_t i1 = (size_t)(ti * 32 + r) * NN + tj * 32 + c;
    size_t i2 = (size_t)(tj * 32 + r) * NN + ti * 32 + c;
    D1[r][c] = P1[i1] + c2 * P2[i1] + c3 * P3[i1];
    D2[r][c] = P1[i2] + c2 * P2[i2] + c3 * P3[i2];
  }
  __syncthreads();
  for (int s = 0; s < 4; ++s) {
    int slot = tid + (s << 8);
    int r = slot >> 5, c = slot & 31;
    size_t i1 = (size_t)(ti * 32 + r) * NN + tj * 32 + c;
    size_t i2 = (size_t)(tj * 32 + r) * NN + ti * 32 + c;
    S[i1] = 0.5f * (D1[r][c] + D2[c][r]);
    S[i2] = 0.5f * (D2[r][c] + D1[c][r]);
  }
}

__global__ void __launch_bounds__(256) k_thr(const float* __restrict__ S,
                                             float* __restrict__ thr) {
  const int b = blockIdx.x;
  const float* Sb = S + (size_t)b * NN * NN;
  const int tid = threadIdx.x;
  float mn = 3.0e38f;
  float rsum = 0.f;
  for (int n = tid; n < NN; n += 256) {
    float d = Sb[(size_t)n * NN + n];
    mn = fminf(mn, d);
    if (n < NN - 1) rsum += d - Sb[(size_t)n * NN + n + 1];
  }
  __shared__ float tmp[4];
  float mtot = blockMinF(mn, tmp);
  float stot = blockSumF(rsum, tmp);
  if (tid == 0) thr[b] = mtot - stot / 1023.0f;
}

__global__ void __launch_bounds__(256) k_stats(const float* __restrict__ S,
                                               const float* __restrict__ thr,
                                               const float* __restrict__ wh1,
                                               const float* __restrict__ wh2,
                                               float* __restrict__ meanv,
                                               float* __restrict__ rstdv) {
  const int n = blockIdx.x;
  const int tid = threadIdx.x;
  double s1 = 0.0, s2 = 0.0;
  for (int b = 0; b < BB; ++b) {
    float t = thr[b];
    float w1 = wh1[b * NN + n];
    const float* Srow = S + ((size_t)b * NN + n) * NN;
    const float* w2p = wh2 + b * NN;
    for (int m = tid; m < NN; m += 256) {
      float e = w1 + w2p[m];
      e = (e > 0.f) ? e : 0.01f * e;
      float att = (Srow[m] > t) ? e : NEGV;
      s1 += (double)att;
      s2 += (double)att * (double)att;
    }
  }
  __shared__ double red[256];
  red[tid] = s1;
  __syncthreads();
  for (int s = 128; s > 0; s >>= 1) {
    if (tid < s) red[tid] += red[tid + s];
    __syncthreads();
  }
  double t1 = red[0];
  __syncthreads();
  red[tid] = s2;
  __syncthreads();
  for (int s = 128; s > 0; s >>= 1) {
    if (tid < s) red[tid] += red[tid + s];
    __syncthreads();
  }
  double t2 = red[0];
  if (tid == 0) {
    double mean = t1 / 8192.0;
    double var = t2 / 8192.0 - mean * mean;
    if (var < 0.0) var = 0.0;
    meanv[n] = (float)mean;
    rstdv[n] = (float)(1.0 / sqrt(var + 1e-5));
  }
}

__global__ void __launch_bounds__(256) k_out(const float* __restrict__ S,
                                             const float* __restrict__ thr,
                                             const float* __restrict__ wh1,
                                             const float* __restrict__ wh2,
                                             const float* __restrict__ meanv,
                                             const float* __restrict__ rstdv,
                                             const float* __restrict__ flag,
                                             void* outv) {
  const int bn = blockIdx.x;
  const int b = bn >> 10;
  const int n = bn & 1023;
  const int tid = threadIdx.x;
  const bool f32m = (flag[0] != 0.0f);
  const float t = thr[b];
  const float w1 = wh1[bn];
  const float* Srow = S + (size_t)bn * NN;
  const float* w2p = wh2 + b * NN;
  float v[4];
  float mx = -3.0e38f;
  for (int w = 0; w < 4; ++w) {
    int m = tid + (w << 8);
    float e = w1 + w2p[m];
    e = (e > 0.f) ? e : 0.01f * e;
    float att = (Srow[m] > t) ? e : NEGV;
    float vv = (att - meanv[n]) * rstdv[n];
    v[w] = vv;
    mx = fmaxf(mx, vv);
  }
  __shared__ float tmp[4];
  float gmx = blockMaxF(mx, tmp);
  float sum = 0.f;
  for (int w = 0; w < 4; ++w) {
    v[w] = __expf(v[w] - gmx);
    sum += v[w];
  }
  float gsum = blockSumF(sum, tmp);
  for (int w = 0; w < 4; ++w) {
    int m = tid + (w << 8);
    float val = v[w] / gsum;
    if (f32m) {
      ((float*)outv)[(size_t)bn * NN + m] = val;
    } else {
      ((bf16*)outv)[(size_t)bn * NN + m] = __float2bfloat16(val);
    }
  }
}

extern "C" void kernel_launch(void* const* d_in, const int* in_sizes, int n_in,
                              void* d_out, int out_size, void* d_ws,
                              size_t ws_size, hipStream_t stream) {
  float* ws = (float*)d_ws;
  const size_t MAT = (size_t)NN * NN;

  // common small block (floats)
  float* sq = ws;               // 8192
  float* wh1 = ws + 8192;       // 8192
  float* wh2 = ws + 16384;      // 8192
  float* thr = ws + 24576;      // 8
  float* meanv = ws + 24584;    // 1024
  float* rstdv = ws + 25608;    // 1024
  float* flag = ws + 26632;     // 8
  float* rsum = ws + 26640;     // 8192
  float* h = ws + 65536;        // 524288

  // fast-path layout (needs 136,577,024 B)
  unsigned short* Ah = (unsigned short*)(ws + 589824);
  unsigned short* Al = (unsigned short*)(ws + 4784128);
  unsigned short* ATh = (unsigned short*)(ws + 8978432);
  unsigned short* ATl = (unsigned short*)(ws + 13172736);
  unsigned short* CTh = (unsigned short*)(ws + 17367040);
  unsigned short* CTl = (unsigned short*)(ws + 21561344);
  float* Sf = ws + 25755648;  // 8388608 floats
  const size_t needed_fast = (25755648ull + 8388608ull) * 4ull;

  // slow-path layout (needs 44,171,264 B, proven available)
  float* A_tmp = ws + 589824;   // 1048576
  float* B_tmp = ws + 1638400;  // 1048576
  float* Ss = ws + 2686976;     // 8388608
  const size_t needed_slow = (2686976ull + 8388608ull) * 4ull;

  // Sentinel A: bf16 0.5 everywhere (overwritten on success)
  k_fill<<<dim3(2048), 256, 0, stream>>>((unsigned short*)d_out, out_size,
                                         (unsigned short)0x3F00);
  if (ws_size < needed_slow) {
    k_fill<<<dim3(2048), 256, 0, stream>>>((unsigned short*)d_out, out_size,
                                           (unsigned short)0xBF80);
    return;
  }

  k_detect<<<dim3(1), 256, 0, stream>>>((const unsigned short*)d_in[0], flag);
  k_h<<<dim3(BB * NN), 64, 0, stream>>>(d_in[0], d_in[1], d_in[2], flag, h, sq,
                                        wh1, wh2);

  if (ws_size >= needed_fast) {
    // ---- fast path: batched split-bf16 MFMA ----
    k_g<<<dim3(16, 16, BB), 256, 0, stream>>>(h, sq, Sf);  // unnormalized A -> Sf
    k_rowsum<<<dim3(BB * NN), 256, 0, stream>>>(Sf, rsum);
    k_split<<<dim3(32, 32, BB), 256, 0, stream>>>(Sf, rsum, Ah, Al, ATh, ATl);
    k_mm1<<<dim3(8, 8, BB), 256, 0, stream>>>(Ah, Al, ATh, ATl, CTh, CTl);
    k_mm2<<<dim3(8, 8, BB), 256, 0, stream>>>(Ah, Al, ATh, ATl, CTh, CTl, Sf);
    k_sym_ip<<<dim3(528, BB), 256, 0, stream>>>(Sf);
    k_thr<<<dim3(BB), 256, 0, stream>>>(Sf, thr);
    k_stats<<<dim3(NN), 256, 0, stream>>>(Sf, thr, wh1, wh2, meanv, rstdv);
    k_out<<<dim3(BB * NN), 256, 0, stream>>>(Sf, thr, wh1, wh2, meanv, rstdv,
                                             flag, d_out);
  } else {
    // ---- slow path: proven per-batch f32 ----
    k_g<<<dim3(16, 16, BB), 256, 0, stream>>>(h, sq, Ss);  // unnormalized A (all b)
    for (int b = 0; b < BB; ++b) {
      float* Sb = Ss + (size_t)b * MAT;
      k_rownorm2<<<dim3(NN), 256, 0, stream>>>(Sb, A_tmp);
      k_gemm64<<<dim3(16, 16), 256, 0, stream>>>(A_tmp, A_tmp, B_tmp);
      k_gemm64<<<dim3(16, 16), 256, 0, stream>>>(A_tmp, B_tmp, Sb);
      k_sym<<<dim3(528), 256, 0, stream>>>(A_tmp, B_tmp, Sb, Sb);
    }
    k_thr<<<dim3(BB), 256, 0, stream>>>(Ss, thr);
    k_stats<<<dim3(NN), 256, 0, stream>>>(Ss, thr, wh1, wh2, meanv, rstdv);
    k_out<<<dim3(BB * NN), 256, 0, stream>>>(Ss, thr, wh1, wh2, meanv, rstdv,
                                             flag, d_out);
  }
}

// Round 5
// 294.250 us; speedup vs baseline: 3.5361x; 1.2370x over previous
//
#include <hip/hip_runtime.h>
#include <hip/hip_bf16.h>

#define BB 8
#define NN 1024
#define FIN 256
#define FOUT 64
#define NEGV (-9000000000000000.0f)

typedef __hip_bfloat16 bf16;
typedef short bf16x8 __attribute__((ext_vector_type(8)));
typedef float f32x4 __attribute__((ext_vector_type(4)));

__device__ __forceinline__ float b2f(bf16 v) { return __bfloat162float(v); }
__device__ __forceinline__ float bu2f(unsigned short u) {
  union { unsigned int i; float f; } c;
  c.i = ((unsigned int)u) << 16;
  return c.f;
}
__device__ __forceinline__ unsigned short f2bu(float v) {
  bf16 t = __float2bfloat16(v);
  return *(unsigned short*)&t;
}

// async global->LDS, 16B per lane; LDS dest is wave-uniform base (+lane*16 by HW)
__device__ __forceinline__ void gload_lds16(const unsigned short* g,
                                            unsigned short* l) {
  __builtin_amdgcn_global_load_lds(
      (__attribute__((address_space(1))) void*)(unsigned long long)(const void*)g,
      (__attribute__((address_space(3))) void*)l, 16, 0, 0);
}

__device__ __forceinline__ float waveRedSum(float v) {
  for (int d = 32; d; d >>= 1) v += __shfl_down(v, d);
  return v;
}
__device__ __forceinline__ float waveRedMax(float v) {
  for (int d = 32; d; d >>= 1) v = fmaxf(v, __shfl_down(v, d));
  return v;
}
__device__ __forceinline__ float waveRedMin(float v) {
  for (int d = 32; d; d >>= 1) v = fminf(v, __shfl_down(v, d));
  return v;
}

__device__ __forceinline__ float blockSumF(float v, float* tmp) {
  __syncthreads();
  v = waveRedSum(v);
  if ((threadIdx.x & 63) == 0) tmp[threadIdx.x >> 6] = v;
  __syncthreads();
  return tmp[0] + tmp[1] + tmp[2] + tmp[3];
}
__device__ __forceinline__ float blockMaxF(float v, float* tmp) {
  __syncthreads();
  v = waveRedMax(v);
  if ((threadIdx.x & 63) == 0) tmp[threadIdx.x >> 6] = v;
  __syncthreads();
  return fmaxf(fmaxf(tmp[0], tmp[1]), fmaxf(tmp[2], tmp[3]));
}
__device__ __forceinline__ float blockMinF(float v, float* tmp) {
  __syncthreads();
  v = waveRedMin(v);
  if ((threadIdx.x & 63) == 0) tmp[threadIdx.x >> 6] = v;
  __syncthreads();
  return fminf(fminf(tmp[0], tmp[1]), fminf(tmp[2], tmp[3]));
}

__global__ void k_fill(unsigned short* o, int n, unsigned short pat) {
  int i = blockIdx.x * blockDim.x + threadIdx.x;
  int stride = gridDim.x * blockDim.x;
  for (; i < n; i += stride) o[i] = pat;
}

__global__ void k_detect(const unsigned short* xu, float* flag) {
  const int tid = threadIdx.x;
  float mx = 0.0f, zc = 0.0f;
  for (int i = tid; i < 8192; i += 256) {
    unsigned short u = xu[i];
    float v = bu2f(u);
    if (u == 0 || u == 0x8000) zc += 1.0f;
    mx = fmaxf(mx, fabsf(v));
  }
  __shared__ float tmp[4];
  float gm = blockMaxF(mx, tmp);
  float gz = blockSumF(zc, tmp);
  if (tid == 0) flag[0] = (gm > 1.0e6f || gz > 2048.0f) ? 1.0f : 0.0f;
}

// h = x @ W per (b,n) row; sq = |h|^2; wh1 = h.a1; wh2 = h.a2
__global__ void __launch_bounds__(64) k_h(const void* xv, const void* Wv,
                                          const void* av,
                                          const float* __restrict__ flag,
                                          float* __restrict__ h,
                                          float* __restrict__ sq,
                                          float* __restrict__ wh1,
                                          float* __restrict__ wh2) {
  const int bn = blockIdx.x;
  const int o = threadIdx.x;
  const bool f32m = (flag[0] != 0.0f);
  __shared__ float xs[FIN];
  if (f32m) {
    const float* xr = (const float*)xv + (size_t)bn * FIN;
    for (int i = o; i < FIN; i += 64) xs[i] = xr[i];
  } else {
    const bf16* xr = (const bf16*)xv + (size_t)bn * FIN;
    for (int i = o; i < FIN; i += 64) xs[i] = b2f(xr[i]);
  }
  __syncthreads();
  float acc = 0.f;
  if (f32m) {
    const float* Wf = (const float*)Wv;
    for (int i = 0; i < FIN; ++i) acc += xs[i] * Wf[i * FOUT + o];
  } else {
    const bf16* Wb = (const bf16*)Wv;
    for (int i = 0; i < FIN; ++i) acc += xs[i] * b2f(Wb[i * FOUT + o]);
  }
  h[(size_t)bn * FOUT + o] = acc;
  float a1, a2;
  if (f32m) {
    a1 = ((const float*)av)[o];
    a2 = ((const float*)av)[FOUT + o];
  } else {
    a1 = b2f(((const bf16*)av)[o]);
    a2 = b2f(((const bf16*)av)[FOUT + o]);
  }
  float s = waveRedSum(acc * acc);
  float w1 = waveRedSum(acc * a1);
  float w2 = waveRedSum(acc * a2);
  if (o == 0) {
    sq[bn] = s;
    wh1[bn] = w1;
    wh2[bn] = w2;
  }
}

// batched: A_un[z][n][m] = exp(-dist); exact 1.0 on diagonal
__global__ void __launch_bounds__(256) k_g(const float* __restrict__ h,
                                           const float* __restrict__ sq,
                                           float* __restrict__ A) {
  const int z = blockIdx.z;
  const float* hb = h + (size_t)z * NN * FOUT;
  const float* sqb = sq + (size_t)z * NN;
  float* Ab = A + (size_t)z * NN * NN;
  const int tr = blockIdx.y * 64, tc = blockIdx.x * 64;
  __shared__ float Ah[64][68];
  __shared__ float Bh[64][68];
  const int tid = threadIdx.x;
  const int tx = tid & 15, ty = tid >> 4;
  for (int s = 0; s < 4; ++s) {
    int slot = tid + (s << 8);
    int r = slot >> 4;
    int c4 = (slot & 15) << 2;
    float4 va = *(const float4*)&hb[(size_t)(tr + r) * FOUT + c4];
    float4 vb = *(const float4*)&hb[(size_t)(tc + r) * FOUT + c4];
    Ah[r][c4] = va.x; Ah[r][c4 + 1] = va.y; Ah[r][c4 + 2] = va.z; Ah[r][c4 + 3] = va.w;
    Bh[r][c4] = vb.x; Bh[r][c4 + 1] = vb.y; Bh[r][c4 + 2] = vb.z; Bh[r][c4 + 3] = vb.w;
  }
  __syncthreads();
  float acc[4][4] = {};
  for (int k = 0; k < 64; ++k) {
    float ra[4], rb[4];
    for (int i = 0; i < 4; ++i) ra[i] = Ah[ty * 4 + i][k];
    for (int j = 0; j < 4; ++j) rb[j] = Bh[tx * 4 + j][k];
    for (int i = 0; i < 4; ++i)
      for (int j = 0; j < 4; ++j) acc[i][j] += ra[i] * rb[j];
  }
  for (int i = 0; i < 4; ++i) {
    int n = tr + ty * 4 + i;
    float sn = sqb[n];
    for (int j = 0; j < 4; ++j) {
      int m = tc + tx * 4 + j;
      float d2 = sn + sqb[m] - 2.0f * acc[i][j];
      float val = (n == m) ? 1.0f : ((d2 > 0.0f) ? expf(-sqrtf(d2)) : 1.0f);
      Ab[(size_t)n * NN + m] = val;
    }
  }
}

// row sums of unnormalized A (all batches)
__global__ void __launch_bounds__(256) k_rowsum(const float* __restrict__ A,
                                                float* __restrict__ rsum) {
  const int bn = blockIdx.x;  // 0..8191
  const float* row = A + (size_t)bn * NN;
  __shared__ float tmp[4];
  const int tid = threadIdx.x;
  float s = 0.f;
  for (int w = 0; w < 4; ++w) s += row[tid + (w << 8)];
  s = blockSumF(s, tmp);
  if (tid == 0) rsum[bn] = fmaxf(s, 1e-12f);
}

// normalize + split hi/lo bf16, normal and transposed layouts
__global__ void __launch_bounds__(256) k_split(const float* __restrict__ A,
                                               const float* __restrict__ rsum,
                                               unsigned short* __restrict__ Ah,
                                               unsigned short* __restrict__ Al,
                                               unsigned short* __restrict__ ATh,
                                               unsigned short* __restrict__ ATl) {
  const int z = blockIdx.z;
  const size_t MAT = (size_t)NN * NN;
  const float* Ab = A + z * MAT;
  const float* rs = rsum + (size_t)z * NN;
  unsigned short* ah = Ah + z * MAT;
  unsigned short* al = Al + z * MAT;
  unsigned short* ath = ATh + z * MAT;
  unsigned short* atl = ATl + z * MAT;
  const int rt = blockIdx.y * 32, ct = blockIdx.x * 32;
  __shared__ unsigned short th[32][33], tl[32][33];
  const int tid = threadIdx.x;
  {
    int r = tid >> 3;
    int c0 = (tid & 7) << 2;
    float4 v = *(const float4*)&Ab[(size_t)(rt + r) * NN + ct + c0];
    float inv = 1.0f / rs[rt + r];
    float vv[4] = {v.x * inv, v.y * inv, v.z * inv, v.w * inv};
    ushort4 h4, l4;
    unsigned short hs[4], ls[4];
    for (int k = 0; k < 4; ++k) {
      hs[k] = f2bu(vv[k]);
      ls[k] = f2bu(vv[k] - bu2f(hs[k]));
      th[r][c0 + k] = hs[k];
      tl[r][c0 + k] = ls[k];
    }
    h4.x = hs[0]; h4.y = hs[1]; h4.z = hs[2]; h4.w = hs[3];
    l4.x = ls[0]; l4.y = ls[1]; l4.z = ls[2]; l4.w = ls[3];
    *(ushort4*)&ah[(size_t)(rt + r) * NN + ct + c0] = h4;
    *(ushort4*)&al[(size_t)(rt + r) * NN + ct + c0] = l4;
  }
  __syncthreads();
  {
    int c = tid >> 3;
    int r0 = (tid & 7) << 2;
    ushort4 h4, l4;
    h4.x = th[r0][c]; h4.y = th[r0 + 1][c]; h4.z = th[r0 + 2][c]; h4.w = th[r0 + 3][c];
    l4.x = tl[r0][c]; l4.y = tl[r0 + 1][c]; l4.z = tl[r0 + 2][c]; l4.w = tl[r0 + 3][c];
    *(ushort4*)&ath[(size_t)(ct + c) * NN + rt + r0] = h4;
    *(ushort4*)&atl[(size_t)(ct + c) * NN + rt + r0] = l4;
  }
}

// MFMA GEMM1: C = A*A (split bf16); writes C transposed hi/lo.
// BK=64, async global_load_lds staging, xor-swizzled LDS granules.
__global__ void __launch_bounds__(256) k_mm1(
    const unsigned short* __restrict__ Ah, const unsigned short* __restrict__ Al,
    const unsigned short* __restrict__ ATh, const unsigned short* __restrict__ ATl,
    unsigned short* __restrict__ CTh, unsigned short* __restrict__ CTl) {
  const int bid = blockIdx.x;
  const int z = bid & 7;  // batch -> XCD (round-robin heuristic)
  const int t6 = bid >> 3;
  const int tr = (t6 >> 3) * 128, tc = (t6 & 7) * 128;
  const size_t MAT = (size_t)NN * NN;
  __shared__ unsigned short sm[32768];  // 4 mats x 128 rows x 64 k (bf16)
  const int tid = threadIdx.x;
  const int wave = tid >> 6, lane = tid & 63;
  const int wm = (wave >> 1) * 64, wn = (wave & 1) * 64;
  const int q = lane >> 4, ln = lane & 15;
  const int rl = lane >> 3;                    // 0..7 (row within 8-row chunk)
  const int gcol = ((lane & 7) ^ rl) << 3;     // swizzled element col offset
  const unsigned short* gp0;
  unsigned short* lb;
  if (wave == 0)      { gp0 = Ah  + z * MAT + (size_t)tr * NN; lb = sm; }
  else if (wave == 1) { gp0 = Al  + z * MAT + (size_t)tr * NN; lb = sm + 8192; }
  else if (wave == 2) { gp0 = ATh + z * MAT + (size_t)tc * NN; lb = sm + 16384; }
  else                { gp0 = ATl + z * MAT + (size_t)tc * NN; lb = sm + 24576; }
  f32x4 acc[4][4];
  for (int i = 0; i < 4; ++i)
    for (int j = 0; j < 4; ++j) acc[i][j] = (f32x4){0.f, 0.f, 0.f, 0.f};
  const int swz = (ln & 7);
  for (int kc = 0; kc < NN; kc += 64) {
    __syncthreads();
    const unsigned short* gpk = gp0 + kc + gcol;
    for (int t = 0; t < 16; ++t)
      gload_lds16(gpk + (size_t)(t * 8 + rl) * NN, lb + t * 512);
    __syncthreads();
    for (int ks = 0; ks < 2; ++ks) {
      const int gq = ((ks * 4 + q) ^ swz) << 3;
      bf16x8 fah[4], fal[4], fbh[4], fbl[4];
      for (int i = 0; i < 4; ++i) {
        int off = (wm + i * 16 + ln) * 64 + gq;
        fah[i] = *(const bf16x8*)&sm[off];
        fal[i] = *(const bf16x8*)&sm[8192 + off];
      }
      for (int j = 0; j < 4; ++j) {
        int off = (wn + j * 16 + ln) * 64 + gq;
        fbh[j] = *(const bf16x8*)&sm[16384 + off];
        fbl[j] = *(const bf16x8*)&sm[24576 + off];
      }
      for (int i = 0; i < 4; ++i)
        for (int j = 0; j < 4; ++j) {
          acc[i][j] = __builtin_amdgcn_mfma_f32_16x16x32_bf16(fah[i], fbh[j], acc[i][j], 0, 0, 0);
          acc[i][j] = __builtin_amdgcn_mfma_f32_16x16x32_bf16(fah[i], fbl[j], acc[i][j], 0, 0, 0);
          acc[i][j] = __builtin_amdgcn_mfma_f32_16x16x32_bf16(fal[i], fbh[j], acc[i][j], 0, 0, 0);
        }
    }
  }
  unsigned short* cth = CTh + z * MAT;
  unsigned short* ctl = CTl + z * MAT;
  for (int i = 0; i < 4; ++i) {
    int m0 = tr + wm + i * 16 + q * 4;
    for (int j = 0; j < 4; ++j) {
      int n = tc + wn + j * 16 + ln;
      ushort4 h4, l4;
      unsigned short hs[4], ls[4];
      for (int reg = 0; reg < 4; ++reg) {
        float v = acc[i][j][reg];
        hs[reg] = f2bu(v);
        ls[reg] = f2bu(v - bu2f(hs[reg]));
      }
      h4.x = hs[0]; h4.y = hs[1]; h4.z = hs[2]; h4.w = hs[3];
      l4.x = ls[0]; l4.y = ls[1]; l4.z = ls[2]; l4.w = ls[3];
      *(ushort4*)&cth[(size_t)n * NN + m0] = h4;
      *(ushort4*)&ctl[(size_t)n * NN + m0] = l4;
    }
  }
}

// MFMA GEMM2: P3 = A*C (split bf16), raw f32 out (combine happens in k_sym2)
__global__ void __launch_bounds__(256) k_mm2(
    const unsigned short* __restrict__ Ah, const unsigned short* __restrict__ Al,
    const unsigned short* __restrict__ CTh, const unsigned short* __restrict__ CTl,
    float* __restrict__ S) {
  const int bid = blockIdx.x;
  const int z = bid & 7;
  const int t6 = bid >> 3;
  const int tr = (t6 >> 3) * 128, tc = (t6 & 7) * 128;
  const size_t MAT = (size_t)NN * NN;
  __shared__ unsigned short sm[32768];
  const int tid = threadIdx.x;
  const int wave = tid >> 6, lane = tid & 63;
  const int wm = (wave >> 1) * 64, wn = (wave & 1) * 64;
  const int q = lane >> 4, ln = lane & 15;
  const int rl = lane >> 3;
  const int gcol = ((lane & 7) ^ rl) << 3;
  const unsigned short* gp0;
  unsigned short* lb;
  if (wave == 0)      { gp0 = Ah  + z * MAT + (size_t)tr * NN; lb = sm; }
  else if (wave == 1) { gp0 = Al  + z * MAT + (size_t)tr * NN; lb = sm + 8192; }
  else if (wave == 2) { gp0 = CTh + z * MAT + (size_t)tc * NN; lb = sm + 16384; }
  else                { gp0 = CTl + z * MAT + (size_t)tc * NN; lb = sm + 24576; }
  f32x4 acc[4][4];
  for (int i = 0; i < 4; ++i)
    for (int j = 0; j < 4; ++j) acc[i][j] = (f32x4){0.f, 0.f, 0.f, 0.f};
  const int swz = (ln & 7);
  for (int kc = 0; kc < NN; kc += 64) {
    __syncthreads();
    const unsigned short* gpk = gp0 + kc + gcol;
    for (int t = 0; t < 16; ++t)
      gload_lds16(gpk + (size_t)(t * 8 + rl) * NN, lb + t * 512);
    __syncthreads();
    for (int ks = 0; ks < 2; ++ks) {
      const int gq = ((ks * 4 + q) ^ swz) << 3;
      bf16x8 fah[4], fal[4], fbh[4], fbl[4];
      for (int i = 0; i < 4; ++i) {
        int off = (wm + i * 16 + ln) * 64 + gq;
        fah[i] = *(const bf16x8*)&sm[off];
        fal[i] = *(const bf16x8*)&sm[8192 + off];
      }
      for (int j = 0; j < 4; ++j) {
        int off = (wn + j * 16 + ln) * 64 + gq;
        fbh[j] = *(const bf16x8*)&sm[16384 + off];
        fbl[j] = *(const bf16x8*)&sm[24576 + off];
      }
      for (int i = 0; i < 4; ++i)
        for (int j = 0; j < 4; ++j) {
          acc[i][j] = __builtin_amdgcn_mfma_f32_16x16x32_bf16(fah[i], fbh[j], acc[i][j], 0, 0, 0);
          acc[i][j] = __builtin_amdgcn_mfma_f32_16x16x32_bf16(fah[i], fbl[j], acc[i][j], 0, 0, 0);
          acc[i][j] = __builtin_amdgcn_mfma_f32_16x16x32_bf16(fal[i], fbh[j], acc[i][j], 0, 0, 0);
        }
    }
  }
  float* Sb = S + z * MAT;
  for (int i = 0; i < 4; ++i) {
    int m0 = tr + wm + i * 16 + q * 4;
    for (int j = 0; j < 4; ++j) {
      int n = tc + wn + j * 16 + ln;
      for (int reg = 0; reg < 4; ++reg)
        Sb[(size_t)(m0 + reg) * NN + n] = acc[i][j][reg];
    }
  }
}

// combine + symmetrize in place:
// S_out = 0.5*(T + T^T), T = A + 0.8*C + 0.64*P3 (P3 currently in S)
__global__ void __launch_bounds__(256) k_sym2(
    const unsigned short* __restrict__ Ah, const unsigned short* __restrict__ Al,
    const unsigned short* __restrict__ CTh, const unsigned short* __restrict__ CTl,
    float* __restrict__ S) {
  const int z = blockIdx.y;
  const size_t base = (size_t)z * NN * NN;
  int p = blockIdx.x;
  int ti = 0, rem = p;
  while (rem >= 32 - ti) {
    rem -= 32 - ti;
    ++ti;
  }
  const int tj = ti + rem;
  __shared__ float D1[32][33], D2[32][33];
  __shared__ float E1[32][33], E2[32][33];
  __shared__ float F1[32][33], F2[32][33];
  const int tid = threadIdx.x;
  for (int s = 0; s < 4; ++s) {
    int slot = tid + (s << 8);
    int r = slot >> 5, c = slot & 31;
    size_t i1 = base + (size_t)(ti * 32 + r) * NN + tj * 32 + c;
    size_t i2 = base + (size_t)(tj * 32 + r) * NN + ti * 32 + c;
    D1[r][c] = S[i1];
    D2[r][c] = S[i2];
    E1[r][c] = bu2f(Ah[i1]) + bu2f(Al[i1]);
    E2[r][c] = bu2f(Ah[i2]) + bu2f(Al[i2]);
    F1[r][c] = bu2f(CTh[i1]) + bu2f(CTl[i1]);
    F2[r][c] = bu2f(CTh[i2]) + bu2f(CTl[i2]);
  }
  __syncthreads();
  for (int s = 0; s < 4; ++s) {
    int slot = tid + (s << 8);
    int r = slot >> 5, c = slot & 31;
    size_t i1 = base + (size_t)(ti * 32 + r) * NN + tj * 32 + c;
    size_t i2 = base + (size_t)(tj * 32 + r) * NN + ti * 32 + c;
    S[i1] = 0.5f * (E1[r][c] + E2[c][r]) + 0.4f * (F2[c][r] + F1[r][c]) +
            0.32f * (D1[r][c] + D2[c][r]);
    S[i2] = 0.5f * (E2[r][c] + E1[c][r]) + 0.4f * (F1[c][r] + F2[r][c]) +
            0.32f * (D2[r][c] + D1[c][r]);
  }
}

__global__ void __launch_bounds__(256) k_thr(const float* __restrict__ S,
                                             float* __restrict__ thr) {
  const int b = blockIdx.x;
  const float* Sb = S + (size_t)b * NN * NN;
  const int tid = threadIdx.x;
  float mn = 3.0e38f;
  float rsum = 0.f;
  for (int n = tid; n < NN; n += 256) {
    float d = Sb[(size_t)n * NN + n];
    mn = fminf(mn, d);
    if (n < NN - 1) rsum += d - Sb[(size_t)n * NN + n + 1];
  }
  __shared__ float tmp[4];
  float mtot = blockMinF(mn, tmp);
  float stot = blockSumF(rsum, tmp);
  if (tid == 0) thr[b] = mtot - stot / 1023.0f;
}

__global__ void __launch_bounds__(256) k_stats(const float* __restrict__ S,
                                               const float* __restrict__ thr,
                                               const float* __restrict__ wh1,
                                               const float* __restrict__ wh2,
                                               float* __restrict__ meanv,
                                               float* __restrict__ rstdv) {
  const int n = blockIdx.x;
  const int tid = threadIdx.x;
  double s1 = 0.0, s2 = 0.0;
  for (int b = 0; b < BB; ++b) {
    float t = thr[b];
    float w1 = wh1[b * NN + n];
    const float* Srow = S + ((size_t)b * NN + n) * NN;
    const float* w2p = wh2 + b * NN;
    for (int m = tid; m < NN; m += 256) {
      float e = w1 + w2p[m];
      e = (e > 0.f) ? e : 0.01f * e;
      float att = (Srow[m] > t) ? e : NEGV;
      s1 += (double)att;
      s2 += (double)att * (double)att;
    }
  }
  __shared__ double red[256];
  red[tid] = s1;
  __syncthreads();
  for (int s = 128; s > 0; s >>= 1) {
    if (tid < s) red[tid] += red[tid + s];
    __syncthreads();
  }
  double t1 = red[0];
  __syncthreads();
  red[tid] = s2;
  __syncthreads();
  for (int s = 128; s > 0; s >>= 1) {
    if (tid < s) red[tid] += red[tid + s];
    __syncthreads();
  }
  double t2 = red[0];
  if (tid == 0) {
    double mean = t1 / 8192.0;
    double var = t2 / 8192.0 - mean * mean;
    if (var < 0.0) var = 0.0;
    meanv[n] = (float)mean;
    rstdv[n] = (float)(1.0 / sqrt(var + 1e-5));
  }
}

__global__ void __launch_bounds__(256) k_out(const float* __restrict__ S,
                                             const float* __restrict__ thr,
                                             const float* __restrict__ wh1,
                                             const float* __restrict__ wh2,
                                             const float* __restrict__ meanv,
                                             const float* __restrict__ rstdv,
                                             const float* __restrict__ flag,
                                             void* outv) {
  const int bn = blockIdx.x;
  const int b = bn >> 10;
  const int n = bn & 1023;
  const int tid = threadIdx.x;
  const bool f32m = (flag[0] != 0.0f);
  const float t = thr[b];
  const float w1 = wh1[bn];
  const float* Srow = S + (size_t)bn * NN;
  const float* w2p = wh2 + b * NN;
  float v[4];
  float mx = -3.0e38f;
  for (int w = 0; w < 4; ++w) {
    int m = tid + (w << 8);
    float e = w1 + w2p[m];
    e = (e > 0.f) ? e : 0.01f * e;
    float att = (Srow[m] > t) ? e : NEGV;
    float vv = (att - meanv[n]) * rstdv[n];
    v[w] = vv;
    mx = fmaxf(mx, vv);
  }
  __shared__ float tmp[4];
  float gmx = blockMaxF(mx, tmp);
  float sum = 0.f;
  for (int w = 0; w < 4; ++w) {
    v[w] = __expf(v[w] - gmx);
    sum += v[w];
  }
  float gsum = blockSumF(sum, tmp);
  for (int w = 0; w < 4; ++w) {
    int m = tid + (w << 8);
    float val = v[w] / gsum;
    if (f32m) {
      ((float*)outv)[(size_t)bn * NN + m] = val;
    } else {
      ((bf16*)outv)[(size_t)bn * NN + m] = __float2bfloat16(val);
    }
  }
}

extern "C" void kernel_launch(void* const* d_in, const int* in_sizes, int n_in,
                              void* d_out, int out_size, void* d_ws,
                              size_t ws_size, hipStream_t stream) {
  float* ws = (float*)d_ws;

  float* sq = ws;               // 8192
  float* wh1 = ws + 8192;       // 8192
  float* wh2 = ws + 16384;      // 8192
  float* thr = ws + 24576;      // 8
  float* meanv = ws + 24584;    // 1024
  float* rstdv = ws + 25608;    // 1024
  float* flag = ws + 26632;     // 8
  float* rsum = ws + 26640;     // 8192
  float* h = ws + 65536;        // 524288

  unsigned short* Ah = (unsigned short*)(ws + 589824);
  unsigned short* Al = (unsigned short*)(ws + 4784128);
  unsigned short* ATh = (unsigned short*)(ws + 8978432);
  unsigned short* ATl = (unsigned short*)(ws + 13172736);
  unsigned short* CTh = (unsigned short*)(ws + 17367040);
  unsigned short* CTl = (unsigned short*)(ws + 21561344);
  float* Sf = ws + 25755648;  // 8388608 floats
  const size_t needed_fast = (25755648ull + 8388608ull) * 4ull;

  // Sentinel: bf16 0.5 everywhere (overwritten by k_out on success)
  k_fill<<<dim3(2048), 256, 0, stream>>>((unsigned short*)d_out, out_size,
                                         (unsigned short)0x3F00);
  if (ws_size < needed_fast) {
    k_fill<<<dim3(2048), 256, 0, stream>>>((unsigned short*)d_out, out_size,
                                           (unsigned short)0xBF80);
    return;
  }

  k_detect<<<dim3(1), 256, 0, stream>>>((const unsigned short*)d_in[0], flag);
  k_h<<<dim3(BB * NN), 64, 0, stream>>>(d_in[0], d_in[1], d_in[2], flag, h, sq,
                                        wh1, wh2);
  k_g<<<dim3(16, 16, BB), 256, 0, stream>>>(h, sq, Sf);  // unnormalized A -> Sf
  k_rowsum<<<dim3(BB * NN), 256, 0, stream>>>(Sf, rsum);
  k_split<<<dim3(32, 32, BB), 256, 0, stream>>>(Sf, rsum, Ah, Al, ATh, ATl);
  k_mm1<<<dim3(512), 256, 0, stream>>>(Ah, Al, ATh, ATl, CTh, CTl);
  k_mm2<<<dim3(512), 256, 0, stream>>>(Ah, Al, CTh, CTl, Sf);
  k_sym2<<<dim3(528, BB), 256, 0, stream>>>(Ah, Al, CTh, CTl, Sf);
  k_thr<<<dim3(BB), 256, 0, stream>>>(Sf, thr);
  k_stats<<<dim3(NN), 256, 0, stream>>>(Sf, thr, wh1, wh2, meanv, rstdv);
  k_out<<<dim3(BB * NN), 256, 0, stream>>>(Sf, thr, wh1, wh2, meanv, rstdv,
                                           flag, d_out);
}